// Round 3
// baseline (6115.204 us; speedup 1.0000x reference)
//
#include <hip/hip_runtime.h>

typedef unsigned int u32;
typedef unsigned long long u64;
typedef float v2f __attribute__((ext_vector_type(2)));

// ---------------------------------------------------------------------------
// helpers
// ---------------------------------------------------------------------------
__device__ __forceinline__ u64 maxu64(u64 a, u64 b) { return a > b ? a : b; }

// DPP-based max-combine stage for a 64-bit key. CTRL: 0xB1 quad_perm xor1,
// 0x4E quad_perm xor2, 0x124 row_ror:4, 0x128 row_ror:8 -> exact butterfly
// max over each 16-lane row on the VALU (no LDS pipe).
template <int CTRL>
__device__ __forceinline__ u64 dpp_max64(u64 k) {
  int slo = __builtin_amdgcn_update_dpp(0, (int)(u32)k, CTRL, 0xF, 0xF, true);
  int shi = __builtin_amdgcn_update_dpp(0, (int)(u32)(k >> 32), CTRL, 0xF, 0xF, true);
  u64 s = ((u64)(u32)shi << 32) | (u32)slo;
  return maxu64(k, s);
}
__device__ __forceinline__ u64 row_max64(u64 k) {
  k = dpp_max64<0xB1>(k);
  k = dpp_max64<0x4E>(k);
  k = dpp_max64<0x124>(k);
  k = dpp_max64<0x128>(k);
  return k;
}

__device__ __forceinline__ float boxlb(float cx, float cy, float cz,
                                       float nx, float xx, float ny, float xy,
                                       float nz, float xz) {
  float gx = fmaxf(fmaxf(nx - cx, cx - xx), 0.0f);
  float gy = fmaxf(fmaxf(ny - cy, cy - xy), 0.0f);
  float gz = fmaxf(fmaxf(nz - cz, cz - xz), 0.0f);
  return gx * gx + gy * gy + gz * gz;
}

// ---------------------------------------------------------------------------
// Kernel 0: Morton bucket sort (unchanged) + zero-init of prog/ticket so each
// graph replay starts clean (stream-ordered before k_mega).
// ---------------------------------------------------------------------------
#define SORT_T 1024

__global__ __launch_bounds__(SORT_T) void k_sort(const float* __restrict__ clouds,
                                                 u32* __restrict__ order,
                                                 u32* __restrict__ bends,
                                                 float* __restrict__ meta,
                                                 u32* prog, int N) {
  const int b = blockIdx.x, tid = threadIdx.x;
  if (b == 0 && tid == 0) { prog[0] = 0u; prog[1] = 0u; prog[2] = 0u; }
  const float* xs = clouds + (size_t)b * 4 * N;
  const float* ys = xs + N;
  const float* zs = ys + N;

  __shared__ u32 hist[2048];
  __shared__ u32 base[2048];
  __shared__ float red[96];
  __shared__ u32 wsum[16];

  float mnx = 3.4e38f, mxx = -3.4e38f, mny = 3.4e38f, mxy = -3.4e38f,
        mnz = 3.4e38f, mxz = -3.4e38f;
  for (int i = tid; i < N; i += SORT_T) {
    float x = xs[i], y = ys[i], z = zs[i];
    mnx = fminf(mnx, x); mxx = fmaxf(mxx, x);
    mny = fminf(mny, y); mxy = fmaxf(mxy, y);
    mnz = fminf(mnz, z); mxz = fmaxf(mxz, z);
  }
#pragma unroll
  for (int s = 1; s < 64; s <<= 1) {
    mnx = fminf(mnx, __shfl_xor(mnx, s, 64)); mxx = fmaxf(mxx, __shfl_xor(mxx, s, 64));
    mny = fminf(mny, __shfl_xor(mny, s, 64)); mxy = fmaxf(mxy, __shfl_xor(mxy, s, 64));
    mnz = fminf(mnz, __shfl_xor(mnz, s, 64)); mxz = fmaxf(mxz, __shfl_xor(mxz, s, 64));
  }
  const int wv = tid >> 6, ln = tid & 63;
  if (ln == 0) {
    red[wv * 6 + 0] = mnx; red[wv * 6 + 1] = mxx;
    red[wv * 6 + 2] = mny; red[wv * 6 + 3] = mxy;
    red[wv * 6 + 4] = mnz; red[wv * 6 + 5] = mxz;
  }
  hist[tid] = 0u; hist[tid + 1024] = 0u;
  __syncthreads();
  float bmnx = red[0], bmxx = red[1], bmny = red[2], bmxy = red[3],
        bmnz = red[4], bmxz = red[5];
#pragma unroll
  for (int w = 1; w < 16; ++w) {
    bmnx = fminf(bmnx, red[w * 6 + 0]); bmxx = fmaxf(bmxx, red[w * 6 + 1]);
    bmny = fminf(bmny, red[w * 6 + 2]); bmxy = fmaxf(bmxy, red[w * 6 + 3]);
    bmnz = fminf(bmnz, red[w * 6 + 4]); bmxz = fmaxf(bmxz, red[w * 6 + 5]);
  }
  const float sx = 16.0f / fmaxf(bmxx - bmnx, 1e-9f);
  const float sy = 16.0f / fmaxf(bmxy - bmny, 1e-9f);
  const float sz = 8.0f / fmaxf(bmxz - bmnz, 1e-9f);
  if (tid == 0) {
    meta[b * 8 + 0] = bmnx; meta[b * 8 + 1] = bmny; meta[b * 8 + 2] = bmnz;
    meta[b * 8 + 3] = fmaxf(bmxx - bmnx, 1e-9f) / 16.0f;
    meta[b * 8 + 4] = fmaxf(bmxy - bmny, 1e-9f) / 16.0f;
    meta[b * 8 + 5] = fmaxf(bmxz - bmnz, 1e-9f) / 8.0f;
  }

  for (int i = tid; i < N; i += SORT_T) {
    int qx = min(15, max(0, (int)((xs[i] - bmnx) * sx)));
    int qy = min(15, max(0, (int)((ys[i] - bmny) * sy)));
    int qz = min(7, max(0, (int)((zs[i] - bmnz) * sz)));
    u32 m = 0; int sh = 0;
#pragma unroll
    for (int bit = 0; bit < 4; ++bit) {
      m |= ((u32)((qx >> bit) & 1)) << sh++;
      m |= ((u32)((qy >> bit) & 1)) << sh++;
      if (bit < 3) m |= ((u32)((qz >> bit) & 1)) << sh++;
    }
    atomicAdd(&hist[m], 1u);
  }
  __syncthreads();

  u32 s0 = hist[2 * tid], s1 = hist[2 * tid + 1];
  u32 ts = s0 + s1;
  u32 x = ts;
#pragma unroll
  for (int d = 1; d < 64; d <<= 1) {
    u32 o = (u32)__shfl_up((int)x, d, 64);
    if (ln >= d) x += o;
  }
  if (ln == 63) wsum[wv] = x;
  __syncthreads();
  u32 wpre = 0;
#pragma unroll
  for (int w = 0; w < 16; ++w) wpre += (w < wv) ? wsum[w] : 0u;
  u32 tbase = wpre + x - ts;
  base[2 * tid] = tbase;
  base[2 * tid + 1] = tbase + s0;
  __syncthreads();

  for (int i = tid; i < N; i += SORT_T) {
    int qx = min(15, max(0, (int)((xs[i] - bmnx) * sx)));
    int qy = min(15, max(0, (int)((ys[i] - bmny) * sy)));
    int qz = min(7, max(0, (int)((zs[i] - bmnz) * sz)));
    u32 m = 0; int sh = 0;
#pragma unroll
    for (int bit = 0; bit < 4; ++bit) {
      m |= ((u32)((qx >> bit) & 1)) << sh++;
      m |= ((u32)((qy >> bit) & 1)) << sh++;
      if (bit < 3) m |= ((u32)((qz >> bit) & 1)) << sh++;
    }
    u32 pos = atomicAdd(&base[m], 1u);
    order[(size_t)b * N + pos] = (u32)i;
  }
  __syncthreads();
  for (int m = tid; m < 2048; m += SORT_T)
    bends[(size_t)b * 2048 + m] = base[m];
}

// ---------------------------------------------------------------------------
// MEGA KERNEL: blocks 0-1 = exact FPS (r2-identical pick sequence); blocks
// 2..255 = persistent workers running ball-query + PointNet pooling per
// keypoint as keypoints become available (producer-consumer overlap).
// Co-residency by construction: 256 blocks <= 256 CUs, any CU hosts >=1
// block of this shape under any packing -> deadlock-free. Keypoints are
// published in batches of 64 via agent-scope (sc1) atomic stores buffered
// in wave-0 lanes + s_waitcnt vmcnt(0) + relaxed progress store; workers
// acquire-load the progress counter (buffer_inv) before reading keyp.
// FPS no longer does per-round global keyp stores (they used to drain at
// every __syncthreads).
// ---------------------------------------------------------------------------
#define KNN_CAP 1024
#define SENTINEL (((u64)0x7F7FFFFFu) << 32)
#define CHUNK 4
#define MEGA_T 1024

// LDS layout (bytes) -- worker stages alias, separated by barriers:
//  knn : cand[1024]u64 @0..8192 | lends[2048]u32 @8192..16384 |
//        blist[2048]u32 @16384..24576 | cnt@24576 bcnt@24580
//  pool: w1l[512]f @0..2048 | gx/gy/gz/gf[32]f @2048..2560 |
//        h1l[32*132]f @2560..19456 | w2l[16*256]f @19456..35840 |
//        pm[256]u32 @35840..36864
//  persistent: sorted32[32]u64 @36864..37120 | shc int @37120
//  fps : slots[2][64]u64 @0..1024
#define SM_BYTES 37376

__device__ void fps_body(const float* __restrict__ clouds,
                         const u32* __restrict__ order,
                         float* keyp, u32* prog, int N, int K, char* smemc) {
  const int b = blockIdx.x, tid = threadIdx.x;
  const float* xs = clouds + (size_t)b * 4 * N;
  const float* ys = xs + N;
  const float* zs = ys + N;

  int oid[16];
  v2f px2[8], py2[8], pz2[8], dd2[8];
#pragma unroll
  for (int j = 0; j < 16; ++j) oid[j] = (int)order[(size_t)b * N + tid * 16 + j];
#pragma unroll
  for (int i = 0; i < 8; ++i) {
    px2[i].x = xs[oid[2 * i]]; px2[i].y = xs[oid[2 * i + 1]];
    py2[i].x = ys[oid[2 * i]]; py2[i].y = ys[oid[2 * i + 1]];
    pz2[i].x = zs[oid[2 * i]]; pz2[i].y = zs[oid[2 * i + 1]];
    dd2[i].x = 1e10f; dd2[i].y = 1e10f;
  }
  float bnx = px2[0].x, bxx = px2[0].x, bny = py2[0].x, bxy = py2[0].x,
        bnz = pz2[0].x, bxz = pz2[0].x;
#pragma unroll
  for (int i = 0; i < 8; ++i) {
    bnx = fminf(bnx, fminf(px2[i].x, px2[i].y));
    bxx = fmaxf(bxx, fmaxf(px2[i].x, px2[i].y));
    bny = fminf(bny, fminf(py2[i].x, py2[i].y));
    bxy = fmaxf(bxy, fmaxf(py2[i].x, py2[i].y));
    bnz = fminf(bnz, fminf(pz2[i].x, pz2[i].y));
    bxz = fmaxf(bxz, fmaxf(pz2[i].x, pz2[i].y));
  }
  // ROW bbox (16 lanes = 256 Morton-adjacent points)
  float rnx = bnx, rxx = bxx, rny = bny, rxy = bxy, rnz = bnz, rxz = bxz;
#pragma unroll
  for (int s = 1; s < 16; s <<= 1) {
    rnx = fminf(rnx, __shfl_xor(rnx, s, 64)); rxx = fmaxf(rxx, __shfl_xor(rxx, s, 64));
    rny = fminf(rny, __shfl_xor(rny, s, 64)); rxy = fmaxf(rxy, __shfl_xor(rxy, s, 64));
    rnz = fminf(rnz, __shfl_xor(rnz, s, 64)); rxz = fmaxf(rxz, __shfl_xor(rxz, s, 64));
  }

  u64 (*slots)[64] = (u64 (*)[64])smemc;
  const int wv = tid >> 6, ln = tid & 63;
  const int row = wv * 4 + (ln >> 4);
  const int q = ln & 15;

  u64 ckey = 0, rkey = 0;
  float cmax = 1e10f, rmax = 1e10f;
  float cx = xs[0], cy = ys[0], cz = zs[0];
  // wave-0 lane l buffers keypoint ((batch<<6)+l); lane 0 starts with kp 0
  float bpx = cx, bpy = cy, bpz = cz;

  for (int t = 1; t < K; ++t) {
    const int par = t & 1;
    float gx = fmaxf(fmaxf(rnx - cx, cx - rxx), 0.0f);
    float gy = fmaxf(fmaxf(rny - cy, cy - rxy), 0.0f);
    float gz = fmaxf(fmaxf(rnz - cz, cz - rxz), 0.0f);
    float lbr = gx * gx + gy * gy + gz * gz;
    if (lbr <= rmax * 1.00001f) {
      float hx = fmaxf(fmaxf(bnx - cx, cx - bxx), 0.0f);
      float hy = fmaxf(fmaxf(bny - cy, cy - bxy), 0.0f);
      float hz = fmaxf(fmaxf(bnz - cz, cz - bxz), 0.0f);
      float lbt = hx * hx + hy * hy + hz * hz;
      if (lbt <= cmax * 1.00001f) {
        v2f m2 = {0.0f, 0.0f};
        {
#pragma clang fp contract(off)
          const v2f c2x = {cx, cx}, c2y = {cy, cy}, c2z = {cz, cz};
#pragma unroll
          for (int i = 0; i < 8; ++i) {
            v2f dx = px2[i] - c2x;
            v2f dy = py2[i] - c2y;
            v2f dz = pz2[i] - c2z;
            v2f d = (dx * dx + dy * dy) + dz * dz;  // pk mul/add, RN, no fma
            v2f nm = __builtin_elementwise_min(dd2[i], d);
            dd2[i] = nm;
            m2 = __builtin_elementwise_max(m2, nm);
          }
        }
        const float m = fmaxf(m2.x, m2.y);
        u32 mi = 0xFFFFFFFFu;
#pragma unroll
        for (int i = 0; i < 8; ++i) {
          if (dd2[i].x == m) mi = min(mi, (u32)oid[2 * i]);
          if (dd2[i].y == m) mi = min(mi, (u32)oid[2 * i + 1]);
        }
        cmax = m;
        ckey = ((u64)__float_as_uint(m) << 32) | (u64)(u32)(~mi);
      }
      rkey = row_max64(ckey);
      rmax = __uint_as_float((u32)(rkey >> 32));
    }
    if (q == 0) slots[par][row] = rkey;
    __syncthreads();
    u64 k0 = slots[par][q];
    u64 k1 = slots[par][q + 16];
    u64 k2 = slots[par][q + 32];
    u64 k3 = slots[par][q + 48];
    u64 g = maxu64(maxu64(k0, k1), maxu64(k2, k3));
    g = row_max64(g);
    const u32 widx = __builtin_amdgcn_readfirstlane(~(u32)g);
    cx = xs[widx]; cy = ys[widx]; cz = zs[widx];
    if (wv == 0) {
      if (ln == (t & 63)) { bpx = cx; bpy = cy; bpz = cz; }
      if ((t & 63) == 63) {
        // batch-publish keypoints [t-63 .. t] (agent-visible sc1 stores)
        u32* kb = (u32*)keyp + ((size_t)b * K + (size_t)(t - 63 + ln)) * 3;
        __hip_atomic_store(kb + 0, __float_as_uint(bpx), __ATOMIC_RELAXED, __HIP_MEMORY_SCOPE_AGENT);
        __hip_atomic_store(kb + 1, __float_as_uint(bpy), __ATOMIC_RELAXED, __HIP_MEMORY_SCOPE_AGENT);
        __hip_atomic_store(kb + 2, __float_as_uint(bpz), __ATOMIC_RELAXED, __HIP_MEMORY_SCOPE_AGENT);
        asm volatile("s_waitcnt vmcnt(0)" ::: "memory");
        if (ln == 0)
          __hip_atomic_store(prog + b, (u32)(t + 1), __ATOMIC_RELAXED, __HIP_MEMORY_SCOPE_AGENT);
      }
    }
  }
  // tail publish (no-op for K % 64 == 0, kept for generality)
  if ((K & 63) != 0 && wv == 0) {
    int base = (K - 1) & ~63;
    int kpt = base + ln;
    if (kpt < K && ln <= ((K - 1) & 63)) {
      u32* kb = (u32*)keyp + ((size_t)b * K + (size_t)kpt) * 3;
      __hip_atomic_store(kb + 0, __float_as_uint(bpx), __ATOMIC_RELAXED, __HIP_MEMORY_SCOPE_AGENT);
      __hip_atomic_store(kb + 1, __float_as_uint(bpy), __ATOMIC_RELAXED, __HIP_MEMORY_SCOPE_AGENT);
      __hip_atomic_store(kb + 2, __float_as_uint(bpz), __ATOMIC_RELAXED, __HIP_MEMORY_SCOPE_AGENT);
    }
    asm volatile("s_waitcnt vmcnt(0)" ::: "memory");
    if (ln == 0)
      __hip_atomic_store(prog + b, (u32)K, __ATOMIC_RELAXED, __HIP_MEMORY_SCOPE_AGENT);
  }
}

// per-keypoint PointNet layer1+layer2+masked max-pool (identical arithmetic
// to the old k_pool; 1024-thread block, compute mapped on tid<256)
template <int M>
__device__ void pool_stage(const float* xs, const float* ys, const float* zs,
                           const float* fs, float kx, float ky, float kz,
                           const u64* s32, const float* __restrict__ w1,
                           const float* __restrict__ w2, float* pooled, int kp,
                           float R2, int colOff, float* w1l, float* gxa,
                           float* gya, float* gza, float* gfa, float* h1l,
                           float* w2l, u32* pm, int tid) {
  constexpr int R = M / 4;
  __syncthreads();  // protect pm/w1l against previous stage's tail reads
  if (tid < 512) w1l[tid] = w1[tid];
  if (tid < 256) pm[tid] = 0u;
  if (tid < M) {
    u64 sl = s32[tid];
    float d2 = __uint_as_float((u32)(sl >> 32));
    u32 idx = (u32)sl;
    float vx = 0.f, vy = 0.f, vz = 0.f, vf = 0.f;
    if (d2 < R2) {
      vx = xs[idx] - kx;
      vy = ys[idx] - ky;
      vz = zs[idx] - kz;
      vf = fs[idx];
    }
    gxa[tid] = vx; gya[tid] = vy; gza[tid] = vz; gfa[tid] = vf;
  }
  __syncthreads();

  if (tid < 256) {
    const int c = tid & 127;
#pragma unroll
    for (int p = 0; p < M / 2; ++p) {
      int r = p * 2 + (tid >> 7);
      float h = fmaf(gfa[r], w1l[384 + c],
                fmaf(gza[r], w1l[256 + c],
                fmaf(gya[r], w1l[128 + c], gxa[r] * w1l[c])));
      h1l[r * 132 + c] = fmaxf(h, 0.0f);
    }
  }

  const int rt = (tid & 255) >> 6;
  const int cg = tid & 63;
  float acc[R][4];
#pragma unroll
  for (int rr = 0; rr < R; ++rr)
#pragma unroll
    for (int cc = 0; cc < 4; ++cc) acc[rr][cc] = 0.0f;

  for (int kt = 0; kt < 8; ++kt) {
    __syncthreads();
    for (int q2 = tid; q2 < 16 * 256; q2 += MEGA_T)
      w2l[q2] = w2[(size_t)(kt * 16 + (q2 >> 8)) * 256 + (q2 & 255)];
    __syncthreads();
    if (tid < 256) {
      for (int k = 0; k < 16; k += 4) {
        float4 hv[R];
#pragma unroll
        for (int rr = 0; rr < R; ++rr)
          hv[rr] = *reinterpret_cast<const float4*>(
              &h1l[(rt * R + rr) * 132 + kt * 16 + k]);
        float4 wv[4];
#pragma unroll
        for (int kk = 0; kk < 4; ++kk)
          wv[kk] = *reinterpret_cast<const float4*>(
              &w2l[(k + kk) * 256 + cg * 4]);
#pragma unroll
        for (int rr = 0; rr < R; ++rr) {
          const float a0 = hv[rr].x, a1 = hv[rr].y, a2 = hv[rr].z, a3 = hv[rr].w;
          acc[rr][0] = fmaf(a3, wv[3].x, fmaf(a2, wv[2].x,
                       fmaf(a1, wv[1].x, fmaf(a0, wv[0].x, acc[rr][0]))));
          acc[rr][1] = fmaf(a3, wv[3].y, fmaf(a2, wv[2].y,
                       fmaf(a1, wv[1].y, fmaf(a0, wv[0].y, acc[rr][1]))));
          acc[rr][2] = fmaf(a3, wv[3].z, fmaf(a2, wv[2].z,
                       fmaf(a1, wv[1].z, fmaf(a0, wv[0].z, acc[rr][2]))));
          acc[rr][3] = fmaf(a3, wv[3].w, fmaf(a2, wv[2].w,
                       fmaf(a1, wv[1].w, fmaf(a0, wv[0].w, acc[rr][3]))));
        }
      }
    }
  }
  if (tid < 256) {
#pragma unroll
    for (int cc = 0; cc < 4; ++cc) {
      float mx = 0.0f;
#pragma unroll
      for (int rr = 0; rr < R; ++rr) mx = fmaxf(mx, acc[rr][cc]);
      atomicMax(&pm[cg * 4 + cc], __float_as_uint(mx));
    }
  }
  __syncthreads();
  if (tid < 256)
    pooled[(size_t)kp * 512 + colOff + tid] = __uint_as_float(pm[tid]);
}

__device__ void worker_body(const float* __restrict__ clouds,
                            const float* keyp, const u32* __restrict__ order,
                            const u32* __restrict__ bends,
                            const float* __restrict__ meta,
                            const float* __restrict__ w1a, const float* __restrict__ w2a,
                            const float* __restrict__ w1b, const float* __restrict__ w2b,
                            float* pooled, float* out, u32* prog, int N, int K,
                            char* smem) {
  const int tid = threadIdx.x;
  u64* cand  = (u64*)(smem);
  u32* lends = (u32*)(smem + 8192);
  u32* blist = (u32*)(smem + 16384);
  int* cnt   = (int*)(smem + 24576);
  int* bcnt  = (int*)(smem + 24580);
  float* w1l = (float*)(smem);
  float* gxa = (float*)(smem + 2048);
  float* gya = (float*)(smem + 2176);
  float* gza = (float*)(smem + 2304);
  float* gfa = (float*)(smem + 2432);
  float* h1l = (float*)(smem + 2560);
  float* w2l = (float*)(smem + 19456);
  u32* pm    = (u32*)(smem + 35840);
  u64* s32   = (u64*)(smem + 36864);
  volatile int* shc = (int*)(smem + 37120);

  const int nch = (2 * K) / CHUNK;
  for (;;) {
    if (tid == 0) *shc = (int)atomicAdd(prog + 2, 1u);
    __syncthreads();
    const int c = *shc;
    if (c >= nch) break;
    for (int j = 0; j < CHUNK; ++j) {
      const int kp = c * CHUNK + j;
      const int b = kp / K;
      const int t = kp - b * K;
      if (tid == 0) {
        while (__hip_atomic_load(prog + b, __ATOMIC_ACQUIRE,
                                 __HIP_MEMORY_SCOPE_AGENT) < (u32)(t + 1))
          __builtin_amdgcn_s_sleep(32);
      }
      __syncthreads();

      const float* xs = clouds + (size_t)b * 4 * N;
      const float* ys = xs + N;
      const float* zs = ys + N;
      const float* fs = zs + N;

      // ---- ball query (exact candidate set; rank selection is a total
      // order on (d2bits<<32|idx) -> insertion-order independent) ----
      if (tid == 0) { *cnt = 0; *bcnt = 0; }
      if (tid < 32) s32[tid] = SENTINEL;
      for (int m = tid; m < 2048; m += MEGA_T)
        lends[m] = bends[(size_t)b * 2048 + m];
      const float kx = keyp[(size_t)kp * 3 + 0];
      const float ky = keyp[(size_t)kp * 3 + 1];
      const float kz = keyp[(size_t)kp * 3 + 2];
      const float bmnx = meta[b * 8 + 0], bmny = meta[b * 8 + 1], bmnz = meta[b * 8 + 2];
      const float csx = meta[b * 8 + 3], csy = meta[b * 8 + 4], csz = meta[b * 8 + 5];
      const float r2b = 2.56f;
      __syncthreads();

      for (int m = tid; m < 2048; m += MEGA_T) {
        u32 qx = (m & 1) | ((m >> 2) & 2) | ((m >> 4) & 4) | ((m >> 6) & 8);
        u32 qy = ((m >> 1) & 1) | ((m >> 3) & 2) | ((m >> 5) & 4) | ((m >> 7) & 8);
        u32 qz = ((m >> 2) & 1) | ((m >> 4) & 2) | ((m >> 6) & 4);
        float lx = bmnx + (float)qx * csx - 1e-3f, hx = bmnx + (float)(qx + 1) * csx + 1e-3f;
        float ly = bmny + (float)qy * csy - 1e-3f, hy = bmny + (float)(qy + 1) * csy + 1e-3f;
        float lz = bmnz + (float)qz * csz - 1e-3f, hz = bmnz + (float)(qz + 1) * csz + 1e-3f;
        if (boxlb(kx, ky, kz, lx, hx, ly, hy, lz, hz) < r2b) {
          u32 s = m ? lends[m - 1] : 0u;
          u32 e = lends[m];
          if (e > s) {
            int p = atomicAdd(bcnt, 1);
            blist[p] = s | (e << 16);
          }
        }
      }
      __syncthreads();

      const int nb = *bcnt;
      for (int bi = 0; bi < nb; ++bi) {
        u32 pk = blist[bi];
        u32 s = pk & 0xFFFFu, e = pk >> 16;
        for (u32 i = s + tid; i < e; i += MEGA_T) {
          u32 pi = order[(size_t)b * N + i];
          float dx = __fsub_rn(xs[pi], kx), dy = __fsub_rn(ys[pi], ky),
                dz = __fsub_rn(zs[pi], kz);
          float d = __fadd_rn(__fadd_rn(__fmul_rn(dx, dx), __fmul_rn(dy, dy)),
                              __fmul_rn(dz, dz));
          if (d < r2b) {
            int p = atomicAdd(cnt, 1);
            if (p < KNN_CAP)
              cand[p] = (((u64)__float_as_uint(d)) << 32) | (u64)pi;
          }
        }
      }
      __syncthreads();
      int n = min(*cnt, KNN_CAP);
      for (int i = tid; i < n; i += MEGA_T) {
        u64 kk = cand[i];
        int r = 0;
        for (int jj = 0; jj < n; ++jj) r += (cand[jj] < kk) ? 1 : 0;
        if (r < 32) s32[r] = kk;
      }
      __syncthreads();
      if (tid < 3) out[(size_t)kp * 131 + tid] = keyp[(size_t)kp * 3 + tid];

      // ---- PointNet pooling, both scales ----
      pool_stage<16>(xs, ys, zs, fs, kx, ky, kz, s32, w1a, w2a, pooled, kp,
                     0.64f, 0, w1l, gxa, gya, gza, gfa, h1l, w2l, pm, tid);
      pool_stage<32>(xs, ys, zs, fs, kx, ky, kz, s32, w1b, w2b, pooled, kp,
                     2.56f, 256, w1l, gxa, gya, gza, gfa, h1l, w2l, pm, tid);
    }
  }
}

__global__ __launch_bounds__(MEGA_T, 4) void k_mega(
    const float* __restrict__ clouds, const u32* __restrict__ order,
    const u32* __restrict__ bends, const float* __restrict__ meta,
    float* keyp, const float* __restrict__ w1a, const float* __restrict__ w2a,
    const float* __restrict__ w1b, const float* __restrict__ w2b,
    float* pooled, float* out, u32* prog, int N, int K) {
  __shared__ __align__(16) char smem[SM_BYTES];
  if (blockIdx.x < 2)
    fps_body(clouds, order, keyp, prog, N, K, smem);
  else
    worker_body(clouds, keyp, order, bends, meta, w1a, w2a, w1b, w2b, pooled,
                out, prog, N, K, smem);
}

// ---------------------------------------------------------------------------
// Kernel 4: fuse GEMM [BK,512]@[512,128] + relu -> d_out features (fp32).
// ---------------------------------------------------------------------------
__global__ __launch_bounds__(256) void k_fuse(const float* __restrict__ pooled,
                                              const float* __restrict__ wf,
                                              float* __restrict__ out) {
  const int m0 = blockIdx.x * 16;
  const int tid = threadIdx.x;
  __shared__ float al[16 * 516];
  __shared__ float wl[32 * 128];

  for (int q = tid; q < 16 * 512; q += 256)
    al[(q >> 9) * 516 + (q & 511)] =
        pooled[(size_t)(m0 + (q >> 9)) * 512 + (q & 511)];

  const int rg = tid >> 5;
  const int cg = tid & 31;
  float acc[2][4];
#pragma unroll
  for (int rr = 0; rr < 2; ++rr)
#pragma unroll
    for (int cc = 0; cc < 4; ++cc) acc[rr][cc] = 0.0f;

  for (int kt = 0; kt < 16; ++kt) {
    __syncthreads();
    for (int q = tid; q < 32 * 128; q += 256)
      wl[q] = wf[(size_t)(kt * 32 + (q >> 7)) * 128 + (q & 127)];
    __syncthreads();
    for (int k = 0; k < 32; k += 4) {
      float4 av[2];
#pragma unroll
      for (int rr = 0; rr < 2; ++rr)
        av[rr] = *reinterpret_cast<const float4*>(
            &al[(rg * 2 + rr) * 516 + kt * 32 + k]);
      float4 wv[4];
#pragma unroll
      for (int kk = 0; kk < 4; ++kk)
        wv[kk] = *reinterpret_cast<const float4*>(&wl[(k + kk) * 128 + cg * 4]);
#pragma unroll
      for (int rr = 0; rr < 2; ++rr) {
        const float a0 = av[rr].x, a1 = av[rr].y, a2 = av[rr].z, a3 = av[rr].w;
        acc[rr][0] = fmaf(a3, wv[3].x, fmaf(a2, wv[2].x,
                     fmaf(a1, wv[1].x, fmaf(a0, wv[0].x, acc[rr][0]))));
        acc[rr][1] = fmaf(a3, wv[3].y, fmaf(a2, wv[2].y,
                     fmaf(a1, wv[1].y, fmaf(a0, wv[0].y, acc[rr][1]))));
        acc[rr][2] = fmaf(a3, wv[3].z, fmaf(a2, wv[2].z,
                     fmaf(a1, wv[1].z, fmaf(a0, wv[0].z, acc[rr][2]))));
        acc[rr][3] = fmaf(a3, wv[3].w, fmaf(a2, wv[2].w,
                     fmaf(a1, wv[1].w, fmaf(a0, wv[0].w, acc[rr][3]))));
      }
    }
  }
#pragma unroll
  for (int rr = 0; rr < 2; ++rr) {
    const size_t row = (size_t)(m0 + rg * 2 + rr);
#pragma unroll
    for (int cc = 0; cc < 4; ++cc)
      out[row * 131 + 3 + cg * 4 + cc] = fmaxf(acc[rr][cc], 0.0f);
  }
}

// ---------------------------------------------------------------------------
extern "C" void kernel_launch(void* const* d_in, const int* in_sizes, int n_in,
                              void* d_out, int out_size, void* d_ws, size_t ws_size,
                              hipStream_t stream) {
  const float* clouds = (const float*)d_in[0];
  const float* w1a = (const float*)d_in[1];
  const float* w2a = (const float*)d_in[2];
  const float* w1b = (const float*)d_in[3];
  const float* w2b = (const float*)d_in[4];
  const float* wfu = (const float*)d_in[5];
  float* out = (float*)d_out;

  const int B = 2;
  const int N = in_sizes[0] / (4 * B);  // 16384
  const int K = out_size / (131 * B);   // 4096
  const int BK = B * K;                 // 8192

  char* ws = (char*)d_ws;
  u32* order = (u32*)ws;                                  // B*N u32
  size_t off = ((size_t)B * N * sizeof(u32) + 255) & ~(size_t)255;
  u32* bends = (u32*)(ws + off);                          // B*2048 u32
  off += (size_t)B * 2048 * sizeof(u32);
  off = (off + 255) & ~(size_t)255;
  float* meta = (float*)(ws + off);                       // B*8 f32
  off += (size_t)B * 8 * sizeof(float);
  off = (off + 255) & ~(size_t)255;
  float* keyp = (float*)(ws + off);                       // BK*3 f32
  off += (size_t)BK * 3 * sizeof(float);
  off = (off + 255) & ~(size_t)255;
  float* pooled = (float*)(ws + off);                     // BK*512 f32
  off += (size_t)BK * 512 * sizeof(float);
  off = (off + 255) & ~(size_t)255;
  u32* prog = (u32*)(ws + off);                           // prog[2] + ticket

  k_sort<<<dim3(B), dim3(SORT_T), 0, stream>>>(clouds, order, bends, meta, prog, N);
  k_mega<<<dim3(256), dim3(MEGA_T), 0, stream>>>(clouds, order, bends, meta,
                                                 keyp, w1a, w2a, w1b, w2b,
                                                 pooled, out, prog, N, K);
  k_fuse<<<dim3(BK / 16), dim3(256), 0, stream>>>(pooled, wfu, out);
}

// Round 4
// 4224.095 us; speedup vs baseline: 1.4477x; 1.4477x over previous
//
#include <hip/hip_runtime.h>

typedef unsigned int u32;
typedef unsigned long long u64;
typedef float v2f __attribute__((ext_vector_type(2)));

// ---------------------------------------------------------------------------
// helpers
// ---------------------------------------------------------------------------
__device__ __forceinline__ u64 maxu64(u64 a, u64 b) { return a > b ? a : b; }

// DPP-based max-combine stage for a 64-bit key. CTRL: 0xB1 quad_perm xor1,
// 0x4E quad_perm xor2, 0x124 row_ror:4, 0x128 row_ror:8 -> exact butterfly
// max over each 16-lane row on the VALU (no LDS pipe).
template <int CTRL>
__device__ __forceinline__ u64 dpp_max64(u64 k) {
  int slo = __builtin_amdgcn_update_dpp(0, (int)(u32)k, CTRL, 0xF, 0xF, true);
  int shi = __builtin_amdgcn_update_dpp(0, (int)(u32)(k >> 32), CTRL, 0xF, 0xF, true);
  u64 s = ((u64)(u32)shi << 32) | (u32)slo;
  return maxu64(k, s);
}
__device__ __forceinline__ u64 row_max64(u64 k) {
  k = dpp_max64<0xB1>(k);
  k = dpp_max64<0x4E>(k);
  k = dpp_max64<0x124>(k);
  k = dpp_max64<0x128>(k);
  return k;
}

__device__ __forceinline__ float boxlb(float cx, float cy, float cz,
                                       float nx, float xx, float ny, float xy,
                                       float nz, float xz) {
  float gx = fmaxf(fmaxf(nx - cx, cx - xx), 0.0f);
  float gy = fmaxf(fmaxf(ny - cy, cy - xy), 0.0f);
  float gz = fmaxf(fmaxf(nz - cz, cz - xz), 0.0f);
  return gx * gx + gy * gy + gz * gz;
}

// ---------------------------------------------------------------------------
// Kernel 0: Morton bucket sort (counting sort, 2048 buckets = 11-bit Morton
// 4/4/3). REVERTED to round-2 form (mega-kernel overlap regressed: CU-packing
// dependent 6.5-47ms instability; ledger now has TWO failed overlap attempts).
// ---------------------------------------------------------------------------
#define SORT_T 1024

__global__ __launch_bounds__(SORT_T) void k_sort(const float* __restrict__ clouds,
                                                 u32* __restrict__ order,
                                                 u32* __restrict__ bends,
                                                 float* __restrict__ meta, int N) {
  const int b = blockIdx.x, tid = threadIdx.x;
  const float* xs = clouds + (size_t)b * 4 * N;
  const float* ys = xs + N;
  const float* zs = ys + N;

  __shared__ u32 hist[2048];
  __shared__ u32 base[2048];
  __shared__ float red[96];
  __shared__ u32 wsum[16];

  float mnx = 3.4e38f, mxx = -3.4e38f, mny = 3.4e38f, mxy = -3.4e38f,
        mnz = 3.4e38f, mxz = -3.4e38f;
  for (int i = tid; i < N; i += SORT_T) {
    float x = xs[i], y = ys[i], z = zs[i];
    mnx = fminf(mnx, x); mxx = fmaxf(mxx, x);
    mny = fminf(mny, y); mxy = fmaxf(mxy, y);
    mnz = fminf(mnz, z); mxz = fmaxf(mxz, z);
  }
#pragma unroll
  for (int s = 1; s < 64; s <<= 1) {
    mnx = fminf(mnx, __shfl_xor(mnx, s, 64)); mxx = fmaxf(mxx, __shfl_xor(mxx, s, 64));
    mny = fminf(mny, __shfl_xor(mny, s, 64)); mxy = fmaxf(mxy, __shfl_xor(mxy, s, 64));
    mnz = fminf(mnz, __shfl_xor(mnz, s, 64)); mxz = fmaxf(mxz, __shfl_xor(mxz, s, 64));
  }
  const int wv = tid >> 6, ln = tid & 63;
  if (ln == 0) {
    red[wv * 6 + 0] = mnx; red[wv * 6 + 1] = mxx;
    red[wv * 6 + 2] = mny; red[wv * 6 + 3] = mxy;
    red[wv * 6 + 4] = mnz; red[wv * 6 + 5] = mxz;
  }
  hist[tid] = 0u; hist[tid + 1024] = 0u;
  __syncthreads();
  float bmnx = red[0], bmxx = red[1], bmny = red[2], bmxy = red[3],
        bmnz = red[4], bmxz = red[5];
#pragma unroll
  for (int w = 1; w < 16; ++w) {
    bmnx = fminf(bmnx, red[w * 6 + 0]); bmxx = fmaxf(bmxx, red[w * 6 + 1]);
    bmny = fminf(bmny, red[w * 6 + 2]); bmxy = fmaxf(bmxy, red[w * 6 + 3]);
    bmnz = fminf(bmnz, red[w * 6 + 4]); bmxz = fmaxf(bmxz, red[w * 6 + 5]);
  }
  const float sx = 16.0f / fmaxf(bmxx - bmnx, 1e-9f);
  const float sy = 16.0f / fmaxf(bmxy - bmny, 1e-9f);
  const float sz = 8.0f / fmaxf(bmxz - bmnz, 1e-9f);
  if (tid == 0) {
    meta[b * 8 + 0] = bmnx; meta[b * 8 + 1] = bmny; meta[b * 8 + 2] = bmnz;
    meta[b * 8 + 3] = fmaxf(bmxx - bmnx, 1e-9f) / 16.0f;  // cell sizes (1/s)
    meta[b * 8 + 4] = fmaxf(bmxy - bmny, 1e-9f) / 16.0f;
    meta[b * 8 + 5] = fmaxf(bmxz - bmnz, 1e-9f) / 8.0f;
  }

  // pass 1: histogram
  for (int i = tid; i < N; i += SORT_T) {
    int qx = min(15, max(0, (int)((xs[i] - bmnx) * sx)));
    int qy = min(15, max(0, (int)((ys[i] - bmny) * sy)));
    int qz = min(7, max(0, (int)((zs[i] - bmnz) * sz)));
    u32 m = 0; int sh = 0;
#pragma unroll
    for (int bit = 0; bit < 4; ++bit) {
      m |= ((u32)((qx >> bit) & 1)) << sh++;
      m |= ((u32)((qy >> bit) & 1)) << sh++;
      if (bit < 3) m |= ((u32)((qz >> bit) & 1)) << sh++;
    }
    atomicAdd(&hist[m], 1u);
  }
  __syncthreads();

  // pass 2: exclusive scan
  u32 s0 = hist[2 * tid], s1 = hist[2 * tid + 1];
  u32 ts = s0 + s1;
  u32 x = ts;
#pragma unroll
  for (int d = 1; d < 64; d <<= 1) {
    u32 o = (u32)__shfl_up((int)x, d, 64);
    if (ln >= d) x += o;
  }
  if (ln == 63) wsum[wv] = x;
  __syncthreads();
  u32 wpre = 0;
#pragma unroll
  for (int w = 0; w < 16; ++w) wpre += (w < wv) ? wsum[w] : 0u;
  u32 tbase = wpre + x - ts;
  base[2 * tid] = tbase;
  base[2 * tid + 1] = tbase + s0;
  __syncthreads();

  // pass 3: scatter
  for (int i = tid; i < N; i += SORT_T) {
    int qx = min(15, max(0, (int)((xs[i] - bmnx) * sx)));
    int qy = min(15, max(0, (int)((ys[i] - bmny) * sy)));
    int qz = min(7, max(0, (int)((zs[i] - bmnz) * sz)));
    u32 m = 0; int sh = 0;
#pragma unroll
    for (int bit = 0; bit < 4; ++bit) {
      m |= ((u32)((qx >> bit) & 1)) << sh++;
      m |= ((u32)((qy >> bit) & 1)) << sh++;
      if (bit < 3) m |= ((u32)((qz >> bit) & 1)) << sh++;
    }
    u32 pos = atomicAdd(&base[m], 1u);
    order[(size_t)b * N + pos] = (u32)i;
  }
  __syncthreads();
  for (int m = tid; m < 2048; m += SORT_T)
    bends[(size_t)b * 2048 + m] = base[m];
}

// ---------------------------------------------------------------------------
// Kernel 1: exact FPS -- REVERTED to the round-2 measured optimum (3820 us):
// 1024 threads x 16 points, pk fp32 pair update, single barrier per pick,
// DPP row reductions, 64 row slots, row-granular pruning. Ledger: double-
// pick, register-tree reduce, LDS coord slots, 512x32, and BOTH mega-kernel
// overlap attempts regressed; DPP reduce (r1, -18%) and 64-row-slots (r2,
// -4%) accepted. Exactness: same key multiset per round -> bitwise-identical
// winner; dd arithmetic contract-off pk RN.
// ---------------------------------------------------------------------------
#define FPS_T 1024

__global__ __launch_bounds__(FPS_T, 4) void k_fps(const float* __restrict__ clouds,
                                                  const u32* __restrict__ order,
                                                  float* __restrict__ keyp,
                                                  int N, int K) {
  const int b = blockIdx.x, tid = threadIdx.x;
  const float* xs = clouds + (size_t)b * 4 * N;
  const float* ys = xs + N;
  const float* zs = ys + N;

  int oid[16];
  v2f px2[8], py2[8], pz2[8], dd2[8];
#pragma unroll
  for (int j = 0; j < 16; ++j) oid[j] = (int)order[(size_t)b * N + tid * 16 + j];
#pragma unroll
  for (int i = 0; i < 8; ++i) {
    px2[i].x = xs[oid[2 * i]]; px2[i].y = xs[oid[2 * i + 1]];
    py2[i].x = ys[oid[2 * i]]; py2[i].y = ys[oid[2 * i + 1]];
    pz2[i].x = zs[oid[2 * i]]; pz2[i].y = zs[oid[2 * i + 1]];
    dd2[i].x = 1e10f; dd2[i].y = 1e10f;
  }
  float bnx = px2[0].x, bxx = px2[0].x, bny = py2[0].x, bxy = py2[0].x,
        bnz = pz2[0].x, bxz = pz2[0].x;
#pragma unroll
  for (int i = 0; i < 8; ++i) {
    bnx = fminf(bnx, fminf(px2[i].x, px2[i].y));
    bxx = fmaxf(bxx, fmaxf(px2[i].x, px2[i].y));
    bny = fminf(bny, fminf(py2[i].x, py2[i].y));
    bxy = fmaxf(bxy, fmaxf(py2[i].x, py2[i].y));
    bnz = fminf(bnz, fminf(pz2[i].x, pz2[i].y));
    bxz = fmaxf(bxz, fmaxf(pz2[i].x, pz2[i].y));
  }
  // ROW bbox (16 lanes = 256 Morton-adjacent points)
  float rnx = bnx, rxx = bxx, rny = bny, rxy = bxy, rnz = bnz, rxz = bxz;
#pragma unroll
  for (int s = 1; s < 16; s <<= 1) {
    rnx = fminf(rnx, __shfl_xor(rnx, s, 64)); rxx = fmaxf(rxx, __shfl_xor(rxx, s, 64));
    rny = fminf(rny, __shfl_xor(rny, s, 64)); rxy = fmaxf(rxy, __shfl_xor(rxy, s, 64));
    rnz = fminf(rnz, __shfl_xor(rnz, s, 64)); rxz = fmaxf(rxz, __shfl_xor(rxz, s, 64));
  }

  __shared__ u64 slots[2][64];
  const int wv = tid >> 6, ln = tid & 63;
  const int row = wv * 4 + (ln >> 4);  // 0..63
  const int q = ln & 15;

  u64 ckey = 0, rkey = 0;
  float cmax = 1e10f, rmax = 1e10f;  // 1e10 forces full update at t=1
  float cx = xs[0], cy = ys[0], cz = zs[0];
  if (tid == 0) {
    float* kb = keyp + (size_t)b * K * 3;
    kb[0] = cx; kb[1] = cy; kb[2] = cz;
  }

  for (int t = 1; t < K; ++t) {
    const int par = t & 1;
    // row-level prune (uniform within 16-lane row)
    float gx = fmaxf(fmaxf(rnx - cx, cx - rxx), 0.0f);
    float gy = fmaxf(fmaxf(rny - cy, cy - rxy), 0.0f);
    float gz = fmaxf(fmaxf(rnz - cz, cz - rxz), 0.0f);
    float lbr = gx * gx + gy * gy + gz * gz;
    if (lbr <= rmax * 1.00001f) {
      // thread-level prune
      float hx = fmaxf(fmaxf(bnx - cx, cx - bxx), 0.0f);
      float hy = fmaxf(fmaxf(bny - cy, cy - bxy), 0.0f);
      float hz = fmaxf(fmaxf(bnz - cz, cz - bxz), 0.0f);
      float lbt = hx * hx + hy * hy + hz * hz;
      if (lbt <= cmax * 1.00001f) {
        v2f m2 = {0.0f, 0.0f};
        {
#pragma clang fp contract(off)
          const v2f c2x = {cx, cx}, c2y = {cy, cy}, c2z = {cz, cz};
#pragma unroll
          for (int i = 0; i < 8; ++i) {
            v2f dx = px2[i] - c2x;
            v2f dy = py2[i] - c2y;
            v2f dz = pz2[i] - c2z;
            v2f d = (dx * dx + dy * dy) + dz * dz;  // pk mul/add, RN, no fma
            v2f nm = __builtin_elementwise_min(dd2[i], d);
            dd2[i] = nm;
            m2 = __builtin_elementwise_max(m2, nm);
          }
        }
        const float m = fmaxf(m2.x, m2.y);
        u32 mi = 0xFFFFFFFFu;
#pragma unroll
        for (int i = 0; i < 8; ++i) {
          if (dd2[i].x == m) mi = min(mi, (u32)oid[2 * i]);
          if (dd2[i].y == m) mi = min(mi, (u32)oid[2 * i + 1]);
        }
        cmax = m;
        ckey = ((u64)__float_as_uint(m) << 32) | (u64)(u32)(~mi);
      }
      // row max: 4 DPP stages, no cross-row LDS shuffles
      rkey = row_max64(ckey);
      rmax = __uint_as_float((u32)(rkey >> 32));
    }
    if (q == 0) slots[par][row] = rkey;
    __syncthreads();
    // global reduce: 4 broadcast slot reads, 3 maxu64, 4 DPP stages
    u64 k0 = slots[par][q];
    u64 k1 = slots[par][q + 16];
    u64 k2 = slots[par][q + 32];
    u64 k3 = slots[par][q + 48];
    u64 g = maxu64(maxu64(k0, k1), maxu64(k2, k3));
    g = row_max64(g);
    const u32 widx = __builtin_amdgcn_readfirstlane(~(u32)g);
    cx = xs[widx]; cy = ys[widx]; cz = zs[widx];
    if (tid == 0) {
      float* kb = keyp + ((size_t)b * K + t) * 3;
      kb[0] = cx; kb[1] = cy; kb[2] = cz;
    }
  }
}

// ---------------------------------------------------------------------------
// Kernel 2 (NEW, fused): per-keypoint ball query + BOTH PointNet pool scales.
// knn part = r2 k_knn verbatim (exact candidate set; rank selection on
// (d2bits<<32|idx) is a total order -> insertion-order independent).
// Pool part = r2 k_pool arithmetic with two bitwise-neutral changes:
//  - VALID-PREFIX ROW SKIP: sorted32 ascending in d2 -> in-ball rows form a
//    prefix [0,v). Rows >= v have g=0 -> h1=+0.0 -> fmaf(0,w,acc)=acc ->
//    acc=+0.0 = the skipped value; max-pool init 0 covers them. Skip guard
//    is wave-uniform (rt=tid>>6). ~80% of layer-2 FLOPs were zero-products.
//  - W2 read direct from L2 (no LDS staging): with <=1 active wave per
//    block, staging 128KB into LDS per block cost more than it saved; W2 is
//    L2-resident (128KB, read-shared). Accumulation order over k unchanged
//    (flat k 0..124 step 4 == old kt*32 tiling; validated absmax 0.0 in r3).
// LDS drops 52KB -> ~25KB -> 6 blocks/CU. Also removes the slots global
// round-trip and two 8192-block launches.
// ---------------------------------------------------------------------------
#define BP_T 256
#define KNN_CAP 1024
#define SENTINEL (((u64)0x7F7FFFFFu) << 32)

template <int M>
__device__ __forceinline__ void pool_scale(
    const float* xs, const float* ys, const float* zs, const float* fs,
    float kx, float ky, float kz, float R2, const float* __restrict__ w1,
    const float* __restrict__ w2, float* __restrict__ pooled, int kp,
    int colOff, const int* vp, const u64* s32, float* w1l, float* gxa,
    float* gya, float* gza, float* gfa, float* h1l, u32* pm, int tid) {
  constexpr int R = M / 4;
  // stage: w1l, g, pm init
  w1l[tid] = w1[tid];
  w1l[tid + 256] = w1[tid + 256];
  pm[tid] = 0u;
  if (tid < M) {
    u64 sl = s32[tid];
    float d2 = __uint_as_float((u32)(sl >> 32));
    u32 idx = (u32)sl;
    float vx = 0.f, vy = 0.f, vz = 0.f, vf = 0.f;
    if (d2 < R2) {
      vx = xs[idx] - kx;
      vy = ys[idx] - ky;
      vz = zs[idx] - kz;
      vf = fs[idx];
    }
    gxa[tid] = vx; gya[tid] = vy; gza[tid] = vz; gfa[tid] = vf;
  }
  __syncthreads();
  const int v = min(*vp, M);  // valid prefix length (wave-uniform scalar)

  // h1 for valid rows only (r = p*2 + (tid>>7) is wave-uniform)
  {
    const int c = tid & 127;
#pragma unroll
    for (int p = 0; p < M / 2; ++p) {
      int r = p * 2 + (tid >> 7);
      if (r < v) {
        float h = fmaf(gfa[r], w1l[384 + c],
                  fmaf(gza[r], w1l[256 + c],
                  fmaf(gya[r], w1l[128 + c], gxa[r] * w1l[c])));
        h1l[r * 132 + c] = fmaxf(h, 0.0f);
      }
    }
  }
  __syncthreads();

  const int rt = tid >> 6;
  const int cg = tid & 63;
  const int rbase = rt * R;
  const int rlim = min(R, max(0, v - rbase));  // wave-uniform
  float acc[R][4];
#pragma unroll
  for (int rr = 0; rr < R; ++rr)
#pragma unroll
    for (int cc = 0; cc < 4; ++cc) acc[rr][cc] = 0.0f;

  if (rlim > 0) {
    for (int k = 0; k < 128; k += 4) {
      float4 wv[4];
#pragma unroll
      for (int kk = 0; kk < 4; ++kk)
        wv[kk] = *reinterpret_cast<const float4*>(&w2[(size_t)(k + kk) * 256 + cg * 4]);
#pragma unroll
      for (int rr = 0; rr < R; ++rr) {
        if (rr < rlim) {
          float4 hv = *reinterpret_cast<const float4*>(&h1l[(rbase + rr) * 132 + k]);
          const float a0 = hv.x, a1 = hv.y, a2 = hv.z, a3 = hv.w;
          acc[rr][0] = fmaf(a3, wv[3].x, fmaf(a2, wv[2].x,
                       fmaf(a1, wv[1].x, fmaf(a0, wv[0].x, acc[rr][0]))));
          acc[rr][1] = fmaf(a3, wv[3].y, fmaf(a2, wv[2].y,
                       fmaf(a1, wv[1].y, fmaf(a0, wv[0].y, acc[rr][1]))));
          acc[rr][2] = fmaf(a3, wv[3].z, fmaf(a2, wv[2].z,
                       fmaf(a1, wv[1].z, fmaf(a0, wv[0].z, acc[rr][2]))));
          acc[rr][3] = fmaf(a3, wv[3].w, fmaf(a2, wv[2].w,
                       fmaf(a1, wv[1].w, fmaf(a0, wv[0].w, acc[rr][3]))));
        }
      }
    }
#pragma unroll
    for (int cc = 0; cc < 4; ++cc) {
      float mx = 0.0f;
#pragma unroll
      for (int rr = 0; rr < R; ++rr) mx = fmaxf(mx, acc[rr][cc]);
      atomicMax(&pm[cg * 4 + cc], __float_as_uint(mx));
    }
  }
  __syncthreads();
  pooled[(size_t)kp * 512 + colOff + tid] = __uint_as_float(pm[tid]);
}

__global__ __launch_bounds__(BP_T) void k_ballpool(
    const float* __restrict__ clouds, const float* __restrict__ keyp,
    const u32* __restrict__ order, const u32* __restrict__ bends,
    const float* __restrict__ meta, const float* __restrict__ w1a,
    const float* __restrict__ w2a, const float* __restrict__ w1b,
    const float* __restrict__ w2b, float* __restrict__ pooled,
    float* __restrict__ out, int N, int K) {
  const int kp = blockIdx.x;
  const int b = kp / K;
  const int tid = threadIdx.x;
  const float* xs = clouds + (size_t)b * 4 * N;
  const float* ys = xs + N;
  const float* zs = ys + N;
  const float* fs = zs + N;

  // union region: knn {cand|lends|blist} aliases pool {w1l|g|h1l|pm}
  __shared__ __align__(16) char sm[24576];
  __shared__ u64 s32[32];
  __shared__ int scnt[4];  // 0:cnt 1:bcnt 2:v_a 3:v_b

  u64* cand  = (u64*)sm;
  u32* lends = (u32*)(sm + 8192);
  u32* blist = (u32*)(sm + 16384);
  float* w1l = (float*)sm;
  float* gxa = (float*)(sm + 2048);
  float* gya = (float*)(sm + 2176);
  float* gza = (float*)(sm + 2304);
  float* gfa = (float*)(sm + 2432);
  float* h1l = (float*)(sm + 2560);
  u32* pm    = (u32*)(sm + 19456);

  const float r2a = 0.64f, r2b = 2.56f;

  if (tid == 0) { scnt[0] = 0; scnt[1] = 0; }
  if (tid < 32) s32[tid] = SENTINEL;
  for (int m = tid; m < 2048; m += BP_T) lends[m] = bends[(size_t)b * 2048 + m];
  const float kx = keyp[(size_t)kp * 3 + 0];
  const float ky = keyp[(size_t)kp * 3 + 1];
  const float kz = keyp[(size_t)kp * 3 + 2];
  const float bmnx = meta[b * 8 + 0], bmny = meta[b * 8 + 1], bmnz = meta[b * 8 + 2];
  const float csx = meta[b * 8 + 3], csy = meta[b * 8 + 4], csz = meta[b * 8 + 5];
  __syncthreads();

  // stage 1: bucket culling
  for (int m = tid; m < 2048; m += BP_T) {
    u32 qx = (m & 1) | ((m >> 2) & 2) | ((m >> 4) & 4) | ((m >> 6) & 8);
    u32 qy = ((m >> 1) & 1) | ((m >> 3) & 2) | ((m >> 5) & 4) | ((m >> 7) & 8);
    u32 qz = ((m >> 2) & 1) | ((m >> 4) & 2) | ((m >> 6) & 4);
    float lx = bmnx + (float)qx * csx - 1e-3f, hx = bmnx + (float)(qx + 1) * csx + 1e-3f;
    float ly = bmny + (float)qy * csy - 1e-3f, hy = bmny + (float)(qy + 1) * csy + 1e-3f;
    float lz = bmnz + (float)qz * csz - 1e-3f, hz = bmnz + (float)(qz + 1) * csz + 1e-3f;
    if (boxlb(kx, ky, kz, lx, hx, ly, hy, lz, hz) < r2b) {
      u32 s = m ? lends[m - 1] : 0u;
      u32 e = lends[m];
      if (e > s) {
        int p = atomicAdd(&scnt[1], 1);
        blist[p] = s | (e << 16);
      }
    }
  }
  __syncthreads();

  // stage 2: scan surviving buckets
  const int nb = scnt[1];
  for (int bi = 0; bi < nb; ++bi) {
    u32 pk = blist[bi];
    u32 s = pk & 0xFFFFu, e = pk >> 16;
    for (u32 i = s + tid; i < e; i += BP_T) {
      u32 pi = order[(size_t)b * N + i];
      float dx = __fsub_rn(xs[pi], kx), dy = __fsub_rn(ys[pi], ky),
            dz = __fsub_rn(zs[pi], kz);
      float d = __fadd_rn(__fadd_rn(__fmul_rn(dx, dx), __fmul_rn(dy, dy)),
                          __fmul_rn(dz, dz));
      if (d < r2b) {
        int p = atomicAdd(&scnt[0], 1);
        if (p < KNN_CAP)
          cand[p] = (((u64)__float_as_uint(d)) << 32) | (u64)pi;
      }
    }
  }
  __syncthreads();
  int n = min(scnt[0], KNN_CAP);
  for (int i = tid; i < n; i += BP_T) {
    u64 kk = cand[i];
    int r = 0;
    for (int j = 0; j < n; ++j) r += (cand[j] < kk) ? 1 : 0;
    if (r < 32) s32[r] = kk;
  }
  __syncthreads();

  // valid-prefix counts (d2 ascending in s32; sentinel fails both tests)
  if (tid < 64) {
    bool oka = (tid < 32) && (__uint_as_float((u32)(s32[tid] >> 32)) < r2a);
    bool okb = (tid < 32) && (__uint_as_float((u32)(s32[tid] >> 32)) < r2b);
    u64 ma = __ballot(oka);
    u64 mb = __ballot(okb);
    if (tid == 0) { scnt[2] = (int)__popcll(ma); scnt[3] = (int)__popcll(mb); }
  }
  if (tid < 3) out[(size_t)kp * 131 + tid] = keyp[(size_t)kp * 3 + tid];
  // (no barrier needed here: pool_scale's staging writes only alias knn
  // arrays whose last reads happened before the rank barrier above; scnt
  // writes are ordered by pool_scale's own first barrier)

  pool_scale<16>(xs, ys, zs, fs, kx, ky, kz, r2a, w1a, w2a, pooled, kp, 0,
                 &scnt[2], s32, w1l, gxa, gya, gza, gfa, h1l, pm, tid);
  pool_scale<32>(xs, ys, zs, fs, kx, ky, kz, r2b, w1b, w2b, pooled, kp, 256,
                 &scnt[3], s32, w1l, gxa, gya, gza, gfa, h1l, pm, tid);
}

// ---------------------------------------------------------------------------
// Kernel 4: fuse GEMM [BK,512]@[512,128] + relu -> d_out features (fp32).
// ---------------------------------------------------------------------------
__global__ __launch_bounds__(256) void k_fuse(const float* __restrict__ pooled,
                                              const float* __restrict__ wf,
                                              float* __restrict__ out) {
  const int m0 = blockIdx.x * 16;
  const int tid = threadIdx.x;
  __shared__ float al[16 * 516];
  __shared__ float wl[32 * 128];

  for (int q = tid; q < 16 * 512; q += 256)
    al[(q >> 9) * 516 + (q & 511)] =
        pooled[(size_t)(m0 + (q >> 9)) * 512 + (q & 511)];

  const int rg = tid >> 5;
  const int cg = tid & 31;
  float acc[2][4];
#pragma unroll
  for (int rr = 0; rr < 2; ++rr)
#pragma unroll
    for (int cc = 0; cc < 4; ++cc) acc[rr][cc] = 0.0f;

  for (int kt = 0; kt < 16; ++kt) {
    __syncthreads();
    for (int q = tid; q < 32 * 128; q += 256)
      wl[q] = wf[(size_t)(kt * 32 + (q >> 7)) * 128 + (q & 127)];
    __syncthreads();
    for (int k = 0; k < 32; k += 4) {
      float4 av[2];
#pragma unroll
      for (int rr = 0; rr < 2; ++rr)
        av[rr] = *reinterpret_cast<const float4*>(
            &al[(rg * 2 + rr) * 516 + kt * 32 + k]);
      float4 wv[4];
#pragma unroll
      for (int kk = 0; kk < 4; ++kk)
        wv[kk] = *reinterpret_cast<const float4*>(&wl[(k + kk) * 128 + cg * 4]);
#pragma unroll
      for (int rr = 0; rr < 2; ++rr) {
        const float a0 = av[rr].x, a1 = av[rr].y, a2 = av[rr].z, a3 = av[rr].w;
        acc[rr][0] = fmaf(a3, wv[3].x, fmaf(a2, wv[2].x,
                     fmaf(a1, wv[1].x, fmaf(a0, wv[0].x, acc[rr][0]))));
        acc[rr][1] = fmaf(a3, wv[3].y, fmaf(a2, wv[2].y,
                     fmaf(a1, wv[1].y, fmaf(a0, wv[0].y, acc[rr][1]))));
        acc[rr][2] = fmaf(a3, wv[3].z, fmaf(a2, wv[2].z,
                     fmaf(a1, wv[1].z, fmaf(a0, wv[0].z, acc[rr][2]))));
        acc[rr][3] = fmaf(a3, wv[3].w, fmaf(a2, wv[2].w,
                     fmaf(a1, wv[1].w, fmaf(a0, wv[0].w, acc[rr][3]))));
      }
    }
  }
#pragma unroll
  for (int rr = 0; rr < 2; ++rr) {
    const size_t row = (size_t)(m0 + rg * 2 + rr);
#pragma unroll
    for (int cc = 0; cc < 4; ++cc)
      out[row * 131 + 3 + cg * 4 + cc] = fmaxf(acc[rr][cc], 0.0f);
  }
}

// ---------------------------------------------------------------------------
extern "C" void kernel_launch(void* const* d_in, const int* in_sizes, int n_in,
                              void* d_out, int out_size, void* d_ws, size_t ws_size,
                              hipStream_t stream) {
  const float* clouds = (const float*)d_in[0];
  const float* w1a = (const float*)d_in[1];
  const float* w2a = (const float*)d_in[2];
  const float* w1b = (const float*)d_in[3];
  const float* w2b = (const float*)d_in[4];
  const float* wfu = (const float*)d_in[5];
  float* out = (float*)d_out;

  const int B = 2;
  const int N = in_sizes[0] / (4 * B);  // 16384
  const int K = out_size / (131 * B);   // 4096
  const int BK = B * K;                 // 8192

  char* ws = (char*)d_ws;
  u32* order = (u32*)ws;                                  // B*N u32
  size_t off = ((size_t)B * N * sizeof(u32) + 255) & ~(size_t)255;
  u32* bends = (u32*)(ws + off);                          // B*2048 u32
  off += (size_t)B * 2048 * sizeof(u32);
  off = (off + 255) & ~(size_t)255;
  float* meta = (float*)(ws + off);                       // B*8 f32
  off += (size_t)B * 8 * sizeof(float);
  off = (off + 255) & ~(size_t)255;
  float* keyp = (float*)(ws + off);                       // BK*3 f32
  off += (size_t)BK * 3 * sizeof(float);
  off = (off + 255) & ~(size_t)255;
  float* pooled = (float*)(ws + off);                     // BK*512 f32

  k_sort<<<dim3(B), dim3(SORT_T), 0, stream>>>(clouds, order, bends, meta, N);
  k_fps<<<dim3(B), dim3(FPS_T), 0, stream>>>(clouds, order, keyp, N, K);
  k_ballpool<<<dim3(BK), dim3(BP_T), 0, stream>>>(clouds, keyp, order, bends,
                                                  meta, w1a, w2a, w1b, w2b,
                                                  pooled, out, N, K);
  k_fuse<<<dim3(BK / 16), dim3(256), 0, stream>>>(pooled, wfu, out);
}

// Round 5
// 4159.999 us; speedup vs baseline: 1.4700x; 1.0154x over previous
//
#include <hip/hip_runtime.h>

typedef unsigned int u32;
typedef unsigned long long u64;
typedef float v2f __attribute__((ext_vector_type(2)));

// ---------------------------------------------------------------------------
// helpers
// ---------------------------------------------------------------------------
__device__ __forceinline__ u64 maxu64(u64 a, u64 b) { return a > b ? a : b; }

// DPP-based max-combine stage for a 64-bit key. CTRL: 0xB1 quad_perm xor1,
// 0x4E quad_perm xor2, 0x124 row_ror:4, 0x128 row_ror:8 -> exact butterfly
// max over each 16-lane row on the VALU (no LDS pipe).
template <int CTRL>
__device__ __forceinline__ u64 dpp_max64(u64 k) {
  int slo = __builtin_amdgcn_update_dpp(0, (int)(u32)k, CTRL, 0xF, 0xF, true);
  int shi = __builtin_amdgcn_update_dpp(0, (int)(u32)(k >> 32), CTRL, 0xF, 0xF, true);
  u64 s = ((u64)(u32)shi << 32) | (u32)slo;
  return maxu64(k, s);
}
__device__ __forceinline__ u64 row_max64(u64 k) {
  k = dpp_max64<0xB1>(k);
  k = dpp_max64<0x4E>(k);
  k = dpp_max64<0x124>(k);
  k = dpp_max64<0x128>(k);
  return k;
}

__device__ __forceinline__ float boxlb(float cx, float cy, float cz,
                                       float nx, float xx, float ny, float xy,
                                       float nz, float xz) {
  float gx = fmaxf(fmaxf(nx - cx, cx - xx), 0.0f);
  float gy = fmaxf(fmaxf(ny - cy, cy - xy), 0.0f);
  float gz = fmaxf(fmaxf(nz - cz, cz - xz), 0.0f);
  return gx * gx + gy * gy + gz * gz;
}

// ---------------------------------------------------------------------------
// Kernel 0: Morton bucket sort (counting sort, 2048 buckets = 11-bit Morton
// 4/4/3). Exports per-bucket end offsets + grid metadata for cell culling.
// ---------------------------------------------------------------------------
#define SORT_T 1024

__global__ __launch_bounds__(SORT_T) void k_sort(const float* __restrict__ clouds,
                                                 u32* __restrict__ order,
                                                 u32* __restrict__ bends,
                                                 float* __restrict__ meta, int N) {
  const int b = blockIdx.x, tid = threadIdx.x;
  const float* xs = clouds + (size_t)b * 4 * N;
  const float* ys = xs + N;
  const float* zs = ys + N;

  __shared__ u32 hist[2048];
  __shared__ u32 base[2048];
  __shared__ float red[96];
  __shared__ u32 wsum[16];

  float mnx = 3.4e38f, mxx = -3.4e38f, mny = 3.4e38f, mxy = -3.4e38f,
        mnz = 3.4e38f, mxz = -3.4e38f;
  for (int i = tid; i < N; i += SORT_T) {
    float x = xs[i], y = ys[i], z = zs[i];
    mnx = fminf(mnx, x); mxx = fmaxf(mxx, x);
    mny = fminf(mny, y); mxy = fmaxf(mxy, y);
    mnz = fminf(mnz, z); mxz = fmaxf(mxz, z);
  }
#pragma unroll
  for (int s = 1; s < 64; s <<= 1) {
    mnx = fminf(mnx, __shfl_xor(mnx, s, 64)); mxx = fmaxf(mxx, __shfl_xor(mxx, s, 64));
    mny = fminf(mny, __shfl_xor(mny, s, 64)); mxy = fmaxf(mxy, __shfl_xor(mxy, s, 64));
    mnz = fminf(mnz, __shfl_xor(mnz, s, 64)); mxz = fmaxf(mxz, __shfl_xor(mxz, s, 64));
  }
  const int wv = tid >> 6, ln = tid & 63;
  if (ln == 0) {
    red[wv * 6 + 0] = mnx; red[wv * 6 + 1] = mxx;
    red[wv * 6 + 2] = mny; red[wv * 6 + 3] = mxy;
    red[wv * 6 + 4] = mnz; red[wv * 6 + 5] = mxz;
  }
  hist[tid] = 0u; hist[tid + 1024] = 0u;
  __syncthreads();
  float bmnx = red[0], bmxx = red[1], bmny = red[2], bmxy = red[3],
        bmnz = red[4], bmxz = red[5];
#pragma unroll
  for (int w = 1; w < 16; ++w) {
    bmnx = fminf(bmnx, red[w * 6 + 0]); bmxx = fmaxf(bmxx, red[w * 6 + 1]);
    bmny = fminf(bmny, red[w * 6 + 2]); bmxy = fmaxf(bmxy, red[w * 6 + 3]);
    bmnz = fminf(bmnz, red[w * 6 + 4]); bmxz = fmaxf(bmxz, red[w * 6 + 5]);
  }
  const float sx = 16.0f / fmaxf(bmxx - bmnx, 1e-9f);
  const float sy = 16.0f / fmaxf(bmxy - bmny, 1e-9f);
  const float sz = 8.0f / fmaxf(bmxz - bmnz, 1e-9f);
  if (tid == 0) {
    meta[b * 8 + 0] = bmnx; meta[b * 8 + 1] = bmny; meta[b * 8 + 2] = bmnz;
    meta[b * 8 + 3] = fmaxf(bmxx - bmnx, 1e-9f) / 16.0f;  // cell sizes (1/s)
    meta[b * 8 + 4] = fmaxf(bmxy - bmny, 1e-9f) / 16.0f;
    meta[b * 8 + 5] = fmaxf(bmxz - bmnz, 1e-9f) / 8.0f;
  }

  // pass 1: histogram
  for (int i = tid; i < N; i += SORT_T) {
    int qx = min(15, max(0, (int)((xs[i] - bmnx) * sx)));
    int qy = min(15, max(0, (int)((ys[i] - bmny) * sy)));
    int qz = min(7, max(0, (int)((zs[i] - bmnz) * sz)));
    u32 m = 0; int sh = 0;
#pragma unroll
    for (int bit = 0; bit < 4; ++bit) {
      m |= ((u32)((qx >> bit) & 1)) << sh++;
      m |= ((u32)((qy >> bit) & 1)) << sh++;
      if (bit < 3) m |= ((u32)((qz >> bit) & 1)) << sh++;
    }
    atomicAdd(&hist[m], 1u);
  }
  __syncthreads();

  // pass 2: exclusive scan
  u32 s0 = hist[2 * tid], s1 = hist[2 * tid + 1];
  u32 ts = s0 + s1;
  u32 x = ts;
#pragma unroll
  for (int d = 1; d < 64; d <<= 1) {
    u32 o = (u32)__shfl_up((int)x, d, 64);
    if (ln >= d) x += o;
  }
  if (ln == 63) wsum[wv] = x;
  __syncthreads();
  u32 wpre = 0;
#pragma unroll
  for (int w = 0; w < 16; ++w) wpre += (w < wv) ? wsum[w] : 0u;
  u32 tbase = wpre + x - ts;
  base[2 * tid] = tbase;
  base[2 * tid + 1] = tbase + s0;
  __syncthreads();

  // pass 3: scatter
  for (int i = tid; i < N; i += SORT_T) {
    int qx = min(15, max(0, (int)((xs[i] - bmnx) * sx)));
    int qy = min(15, max(0, (int)((ys[i] - bmny) * sy)));
    int qz = min(7, max(0, (int)((zs[i] - bmnz) * sz)));
    u32 m = 0; int sh = 0;
#pragma unroll
    for (int bit = 0; bit < 4; ++bit) {
      m |= ((u32)((qx >> bit) & 1)) << sh++;
      m |= ((u32)((qy >> bit) & 1)) << sh++;
      if (bit < 3) m |= ((u32)((qz >> bit) & 1)) << sh++;
    }
    u32 pos = atomicAdd(&base[m], 1u);
    order[(size_t)b * N + pos] = (u32)i;
  }
  __syncthreads();
  for (int m = tid; m < 2048; m += SORT_T)
    bends[(size_t)b * 2048 + m] = base[m];
}

// ---------------------------------------------------------------------------
// Kernel 1: exact FPS -- round-2 measured optimum (3820 us), UNCHANGED.
// Issue-bound analysis (r4): VALUBusy ~58% of the 2 active CUs; round time
// ~2240 cyc matches 4 updater waves/SIMD x ~220 cyc issue. Payload-carry
// coords and mi-scan deferral are arithmetic washes under this model.
// Ledger: double-pick, register-tree reduce, LDS coord slots, 512x32, both
// overlap mega-kernels regressed; DPP reduce (r1) + 64-row-slots (r2)
// accepted. Exactness: same key multiset per round -> bitwise winner.
// ---------------------------------------------------------------------------
#define FPS_T 1024

__global__ __launch_bounds__(FPS_T, 4) void k_fps(const float* __restrict__ clouds,
                                                  const u32* __restrict__ order,
                                                  float* __restrict__ keyp,
                                                  int N, int K) {
  const int b = blockIdx.x, tid = threadIdx.x;
  const float* xs = clouds + (size_t)b * 4 * N;
  const float* ys = xs + N;
  const float* zs = ys + N;

  int oid[16];
  v2f px2[8], py2[8], pz2[8], dd2[8];
#pragma unroll
  for (int j = 0; j < 16; ++j) oid[j] = (int)order[(size_t)b * N + tid * 16 + j];
#pragma unroll
  for (int i = 0; i < 8; ++i) {
    px2[i].x = xs[oid[2 * i]]; px2[i].y = xs[oid[2 * i + 1]];
    py2[i].x = ys[oid[2 * i]]; py2[i].y = ys[oid[2 * i + 1]];
    pz2[i].x = zs[oid[2 * i]]; pz2[i].y = zs[oid[2 * i + 1]];
    dd2[i].x = 1e10f; dd2[i].y = 1e10f;
  }
  float bnx = px2[0].x, bxx = px2[0].x, bny = py2[0].x, bxy = py2[0].x,
        bnz = pz2[0].x, bxz = pz2[0].x;
#pragma unroll
  for (int i = 0; i < 8; ++i) {
    bnx = fminf(bnx, fminf(px2[i].x, px2[i].y));
    bxx = fmaxf(bxx, fmaxf(px2[i].x, px2[i].y));
    bny = fminf(bny, fminf(py2[i].x, py2[i].y));
    bxy = fmaxf(bxy, fmaxf(py2[i].x, py2[i].y));
    bnz = fminf(bnz, fminf(pz2[i].x, pz2[i].y));
    bxz = fmaxf(bxz, fmaxf(pz2[i].x, pz2[i].y));
  }
  // ROW bbox (16 lanes = 256 Morton-adjacent points)
  float rnx = bnx, rxx = bxx, rny = bny, rxy = bxy, rnz = bnz, rxz = bxz;
#pragma unroll
  for (int s = 1; s < 16; s <<= 1) {
    rnx = fminf(rnx, __shfl_xor(rnx, s, 64)); rxx = fmaxf(rxx, __shfl_xor(rxx, s, 64));
    rny = fminf(rny, __shfl_xor(rny, s, 64)); rxy = fmaxf(rxy, __shfl_xor(rxy, s, 64));
    rnz = fminf(rnz, __shfl_xor(rnz, s, 64)); rxz = fmaxf(rxz, __shfl_xor(rxz, s, 64));
  }

  __shared__ u64 slots[2][64];
  const int wv = tid >> 6, ln = tid & 63;
  const int row = wv * 4 + (ln >> 4);  // 0..63
  const int q = ln & 15;

  u64 ckey = 0, rkey = 0;
  float cmax = 1e10f, rmax = 1e10f;  // 1e10 forces full update at t=1
  float cx = xs[0], cy = ys[0], cz = zs[0];
  if (tid == 0) {
    float* kb = keyp + (size_t)b * K * 3;
    kb[0] = cx; kb[1] = cy; kb[2] = cz;
  }

  for (int t = 1; t < K; ++t) {
    const int par = t & 1;
    // row-level prune (uniform within 16-lane row)
    float gx = fmaxf(fmaxf(rnx - cx, cx - rxx), 0.0f);
    float gy = fmaxf(fmaxf(rny - cy, cy - rxy), 0.0f);
    float gz = fmaxf(fmaxf(rnz - cz, cz - rxz), 0.0f);
    float lbr = gx * gx + gy * gy + gz * gz;
    if (lbr <= rmax * 1.00001f) {
      // thread-level prune
      float hx = fmaxf(fmaxf(bnx - cx, cx - bxx), 0.0f);
      float hy = fmaxf(fmaxf(bny - cy, cy - bxy), 0.0f);
      float hz = fmaxf(fmaxf(bnz - cz, cz - bxz), 0.0f);
      float lbt = hx * hx + hy * hy + hz * hz;
      if (lbt <= cmax * 1.00001f) {
        v2f m2 = {0.0f, 0.0f};
        {
#pragma clang fp contract(off)
          const v2f c2x = {cx, cx}, c2y = {cy, cy}, c2z = {cz, cz};
#pragma unroll
          for (int i = 0; i < 8; ++i) {
            v2f dx = px2[i] - c2x;
            v2f dy = py2[i] - c2y;
            v2f dz = pz2[i] - c2z;
            v2f d = (dx * dx + dy * dy) + dz * dz;  // pk mul/add, RN, no fma
            v2f nm = __builtin_elementwise_min(dd2[i], d);
            dd2[i] = nm;
            m2 = __builtin_elementwise_max(m2, nm);
          }
        }
        const float m = fmaxf(m2.x, m2.y);
        u32 mi = 0xFFFFFFFFu;
#pragma unroll
        for (int i = 0; i < 8; ++i) {
          if (dd2[i].x == m) mi = min(mi, (u32)oid[2 * i]);
          if (dd2[i].y == m) mi = min(mi, (u32)oid[2 * i + 1]);
        }
        cmax = m;
        ckey = ((u64)__float_as_uint(m) << 32) | (u64)(u32)(~mi);
      }
      // row max: 4 DPP stages, no cross-row LDS shuffles
      rkey = row_max64(ckey);
      rmax = __uint_as_float((u32)(rkey >> 32));
    }
    if (q == 0) slots[par][row] = rkey;
    __syncthreads();
    // global reduce: 4 broadcast slot reads, 3 maxu64, 4 DPP stages
    u64 k0 = slots[par][q];
    u64 k1 = slots[par][q + 16];
    u64 k2 = slots[par][q + 32];
    u64 k3 = slots[par][q + 48];
    u64 g = maxu64(maxu64(k0, k1), maxu64(k2, k3));
    g = row_max64(g);
    const u32 widx = __builtin_amdgcn_readfirstlane(~(u32)g);
    cx = xs[widx]; cy = ys[widx]; cz = zs[widx];
    if (tid == 0) {
      float* kb = keyp + ((size_t)b * K + t) * 3;
      kb[0] = cx; kb[1] = cy; kb[2] = cz;
    }
  }
}

// ---------------------------------------------------------------------------
// Kernel 2: fused ball query + both PointNet pool scales (r4 structure).
// THIS ROUND: bucket culling via DIRECT CELL-RANGE ENUMERATION instead of
// scanning all 2048 buckets with a staged lends copy (8 KB x 8192 blocks =
// 64 MB L2 traffic). Conservative [qx0..qx1]x[qy0..qy1]x[qz0..qz1] ranges
// (+-1 cell margin >> fp division error) enumerate <=~160 cells; each gets
// the IDENTICAL expanded-AABB boxlb test; bends[m-1]/bends[m] fetched only
// for passing cells. Superset iterator + same test -> identical candidate
// set -> rank selection, pooling, output bitwise unchanged.
// Pool part unchanged from r4 (valid-prefix row skip, W2 direct from L2).
// ---------------------------------------------------------------------------
#define BP_T 256
#define KNN_CAP 1024
#define SENTINEL (((u64)0x7F7FFFFFu) << 32)

template <int M>
__device__ __forceinline__ void pool_scale(
    const float* xs, const float* ys, const float* zs, const float* fs,
    float kx, float ky, float kz, float R2, const float* __restrict__ w1,
    const float* __restrict__ w2, float* __restrict__ pooled, int kp,
    int colOff, const int* vp, const u64* s32, float* w1l, float* gxa,
    float* gya, float* gza, float* gfa, float* h1l, u32* pm, int tid) {
  constexpr int R = M / 4;
  // stage: w1l, g, pm init
  w1l[tid] = w1[tid];
  w1l[tid + 256] = w1[tid + 256];
  pm[tid] = 0u;
  if (tid < M) {
    u64 sl = s32[tid];
    float d2 = __uint_as_float((u32)(sl >> 32));
    u32 idx = (u32)sl;
    float vx = 0.f, vy = 0.f, vz = 0.f, vf = 0.f;
    if (d2 < R2) {
      vx = xs[idx] - kx;
      vy = ys[idx] - ky;
      vz = zs[idx] - kz;
      vf = fs[idx];
    }
    gxa[tid] = vx; gya[tid] = vy; gza[tid] = vz; gfa[tid] = vf;
  }
  __syncthreads();
  const int v = min(*vp, M);  // valid prefix length (wave-uniform scalar)

  // h1 for valid rows only (r = p*2 + (tid>>7) is wave-uniform)
  {
    const int c = tid & 127;
#pragma unroll
    for (int p = 0; p < M / 2; ++p) {
      int r = p * 2 + (tid >> 7);
      if (r < v) {
        float h = fmaf(gfa[r], w1l[384 + c],
                  fmaf(gza[r], w1l[256 + c],
                  fmaf(gya[r], w1l[128 + c], gxa[r] * w1l[c])));
        h1l[r * 132 + c] = fmaxf(h, 0.0f);
      }
    }
  }
  __syncthreads();

  const int rt = tid >> 6;
  const int cg = tid & 63;
  const int rbase = rt * R;
  const int rlim = min(R, max(0, v - rbase));  // wave-uniform
  float acc[R][4];
#pragma unroll
  for (int rr = 0; rr < R; ++rr)
#pragma unroll
    for (int cc = 0; cc < 4; ++cc) acc[rr][cc] = 0.0f;

  if (rlim > 0) {
    for (int k = 0; k < 128; k += 4) {
      float4 wv[4];
#pragma unroll
      for (int kk = 0; kk < 4; ++kk)
        wv[kk] = *reinterpret_cast<const float4*>(&w2[(size_t)(k + kk) * 256 + cg * 4]);
#pragma unroll
      for (int rr = 0; rr < R; ++rr) {
        if (rr < rlim) {
          float4 hv = *reinterpret_cast<const float4*>(&h1l[(rbase + rr) * 132 + k]);
          const float a0 = hv.x, a1 = hv.y, a2 = hv.z, a3 = hv.w;
          acc[rr][0] = fmaf(a3, wv[3].x, fmaf(a2, wv[2].x,
                       fmaf(a1, wv[1].x, fmaf(a0, wv[0].x, acc[rr][0]))));
          acc[rr][1] = fmaf(a3, wv[3].y, fmaf(a2, wv[2].y,
                       fmaf(a1, wv[1].y, fmaf(a0, wv[0].y, acc[rr][1]))));
          acc[rr][2] = fmaf(a3, wv[3].z, fmaf(a2, wv[2].z,
                       fmaf(a1, wv[1].z, fmaf(a0, wv[0].z, acc[rr][2]))));
          acc[rr][3] = fmaf(a3, wv[3].w, fmaf(a2, wv[2].w,
                       fmaf(a1, wv[1].w, fmaf(a0, wv[0].w, acc[rr][3]))));
        }
      }
    }
#pragma unroll
    for (int cc = 0; cc < 4; ++cc) {
      float mx = 0.0f;
#pragma unroll
      for (int rr = 0; rr < R; ++rr) mx = fmaxf(mx, acc[rr][cc]);
      atomicMax(&pm[cg * 4 + cc], __float_as_uint(mx));
    }
  }
  __syncthreads();
  pooled[(size_t)kp * 512 + colOff + tid] = __uint_as_float(pm[tid]);
}

__global__ __launch_bounds__(BP_T) void k_ballpool(
    const float* __restrict__ clouds, const float* __restrict__ keyp,
    const u32* __restrict__ order, const u32* __restrict__ bends,
    const float* __restrict__ meta, const float* __restrict__ w1a,
    const float* __restrict__ w2a, const float* __restrict__ w1b,
    const float* __restrict__ w2b, float* __restrict__ pooled,
    float* __restrict__ out, int N, int K) {
  const int kp = blockIdx.x;
  const int b = kp / K;
  const int tid = threadIdx.x;
  const float* xs = clouds + (size_t)b * 4 * N;
  const float* ys = xs + N;
  const float* zs = ys + N;
  const float* fs = zs + N;

  // union region: knn {cand|blist} aliases pool {w1l|g|h1l|pm}
  __shared__ __align__(16) char sm[24576];
  __shared__ u64 s32[32];
  __shared__ int scnt[4];  // 0:cnt 1:bcnt 2:v_a 3:v_b

  u64* cand  = (u64*)sm;
  u32* blist = (u32*)(sm + 8192);  // <=2048 entries (degenerate worst case)
  float* w1l = (float*)sm;
  float* gxa = (float*)(sm + 2048);
  float* gya = (float*)(sm + 2176);
  float* gza = (float*)(sm + 2304);
  float* gfa = (float*)(sm + 2432);
  float* h1l = (float*)(sm + 2560);
  u32* pm    = (u32*)(sm + 19456);

  const float r2a = 0.64f, r2b = 2.56f;

  if (tid == 0) { scnt[0] = 0; scnt[1] = 0; }
  if (tid < 32) s32[tid] = SENTINEL;
  const float kx = keyp[(size_t)kp * 3 + 0];
  const float ky = keyp[(size_t)kp * 3 + 1];
  const float kz = keyp[(size_t)kp * 3 + 2];
  const float bmnx = meta[b * 8 + 0], bmny = meta[b * 8 + 1], bmnz = meta[b * 8 + 2];
  const float csx = meta[b * 8 + 3], csy = meta[b * 8 + 4], csz = meta[b * 8 + 5];
  __syncthreads();

  // stage 1: direct cell-range enumeration (conservative superset iterator;
  // the per-cell boxlb test below is IDENTICAL to the old 2048-bucket scan,
  // so the surviving-bucket set is exactly the same).
  {
    const float rb = sqrtf(r2b) + 2e-3f;  // radius + both AABB expansions
    const int qx0 = max(0, (int)floorf((kx - rb - bmnx) / csx) - 1);
    const int qx1 = min(15, (int)floorf((kx + rb - bmnx) / csx) + 1);
    const int qy0 = max(0, (int)floorf((ky - rb - bmny) / csy) - 1);
    const int qy1 = min(15, (int)floorf((ky + rb - bmny) / csy) + 1);
    const int qz0 = max(0, (int)floorf((kz - rb - bmnz) / csz) - 1);
    const int qz1 = min(7, (int)floorf((kz + rb - bmnz) / csz) + 1);
    const int nx = qx1 - qx0 + 1, ny = qy1 - qy0 + 1, nz = qz1 - qz0 + 1;
    const int ncell = nx * ny * nz;
    for (int c = tid; c < ncell; c += BP_T) {
      int ix = c % nx;
      int rem = c / nx;
      u32 qx = (u32)(qx0 + ix);
      u32 qy = (u32)(qy0 + rem % ny);
      u32 qz = (u32)(qz0 + rem / ny);
      u32 m = 0; int sh = 0;
#pragma unroll
      for (int bit = 0; bit < 4; ++bit) {
        m |= ((qx >> bit) & 1) << sh++;
        m |= ((qy >> bit) & 1) << sh++;
        if (bit < 3) m |= ((qz >> bit) & 1) << sh++;
      }
      float lx = bmnx + (float)qx * csx - 1e-3f, hx = bmnx + (float)(qx + 1) * csx + 1e-3f;
      float ly = bmny + (float)qy * csy - 1e-3f, hy = bmny + (float)(qy + 1) * csy + 1e-3f;
      float lz = bmnz + (float)qz * csz - 1e-3f, hz = bmnz + (float)(qz + 1) * csz + 1e-3f;
      if (boxlb(kx, ky, kz, lx, hx, ly, hy, lz, hz) < r2b) {
        u32 e = bends[(size_t)b * 2048 + m];
        u32 s = m ? bends[(size_t)b * 2048 + m - 1] : 0u;
        if (e > s) {
          int p = atomicAdd(&scnt[1], 1);
          blist[p] = s | (e << 16);
        }
      }
    }
  }
  __syncthreads();

  // stage 2: scan surviving buckets
  const int nb = scnt[1];
  for (int bi = 0; bi < nb; ++bi) {
    u32 pk = blist[bi];
    u32 s = pk & 0xFFFFu, e = pk >> 16;
    for (u32 i = s + tid; i < e; i += BP_T) {
      u32 pi = order[(size_t)b * N + i];
      float dx = __fsub_rn(xs[pi], kx), dy = __fsub_rn(ys[pi], ky),
            dz = __fsub_rn(zs[pi], kz);
      float d = __fadd_rn(__fadd_rn(__fmul_rn(dx, dx), __fmul_rn(dy, dy)),
                          __fmul_rn(dz, dz));
      if (d < r2b) {
        int p = atomicAdd(&scnt[0], 1);
        if (p < KNN_CAP)
          cand[p] = (((u64)__float_as_uint(d)) << 32) | (u64)pi;
      }
    }
  }
  __syncthreads();
  int n = min(scnt[0], KNN_CAP);
  for (int i = tid; i < n; i += BP_T) {
    u64 kk = cand[i];
    int r = 0;
    for (int j = 0; j < n; ++j) r += (cand[j] < kk) ? 1 : 0;
    if (r < 32) s32[r] = kk;
  }
  __syncthreads();

  // valid-prefix counts (d2 ascending in s32; sentinel fails both tests)
  if (tid < 64) {
    bool oka = (tid < 32) && (__uint_as_float((u32)(s32[tid] >> 32)) < r2a);
    bool okb = (tid < 32) && (__uint_as_float((u32)(s32[tid] >> 32)) < r2b);
    u64 ma = __ballot(oka);
    u64 mb = __ballot(okb);
    if (tid == 0) { scnt[2] = (int)__popcll(ma); scnt[3] = (int)__popcll(mb); }
  }
  if (tid < 3) out[(size_t)kp * 131 + tid] = keyp[(size_t)kp * 3 + tid];
  // (no barrier needed: pool_scale's staging writes only alias knn arrays
  // whose last reads happened before the rank barrier above; scnt writes
  // are ordered by pool_scale's own first barrier)

  pool_scale<16>(xs, ys, zs, fs, kx, ky, kz, r2a, w1a, w2a, pooled, kp, 0,
                 &scnt[2], s32, w1l, gxa, gya, gza, gfa, h1l, pm, tid);
  pool_scale<32>(xs, ys, zs, fs, kx, ky, kz, r2b, w1b, w2b, pooled, kp, 256,
                 &scnt[3], s32, w1l, gxa, gya, gza, gfa, h1l, pm, tid);
}

// ---------------------------------------------------------------------------
// Kernel 4: fuse GEMM [BK,512]@[512,128] + relu -> d_out features (fp32).
// ---------------------------------------------------------------------------
__global__ __launch_bounds__(256) void k_fuse(const float* __restrict__ pooled,
                                              const float* __restrict__ wf,
                                              float* __restrict__ out) {
  const int m0 = blockIdx.x * 16;
  const int tid = threadIdx.x;
  __shared__ float al[16 * 516];
  __shared__ float wl[32 * 128];

  for (int q = tid; q < 16 * 512; q += 256)
    al[(q >> 9) * 516 + (q & 511)] =
        pooled[(size_t)(m0 + (q >> 9)) * 512 + (q & 511)];

  const int rg = tid >> 5;
  const int cg = tid & 31;
  float acc[2][4];
#pragma unroll
  for (int rr = 0; rr < 2; ++rr)
#pragma unroll
    for (int cc = 0; cc < 4; ++cc) acc[rr][cc] = 0.0f;

  for (int kt = 0; kt < 16; ++kt) {
    __syncthreads();
    for (int q = tid; q < 32 * 128; q += 256)
      wl[q] = wf[(size_t)(kt * 32 + (q >> 7)) * 128 + (q & 127)];
    __syncthreads();
    for (int k = 0; k < 32; k += 4) {
      float4 av[2];
#pragma unroll
      for (int rr = 0; rr < 2; ++rr)
        av[rr] = *reinterpret_cast<const float4*>(
            &al[(rg * 2 + rr) * 516 + kt * 32 + k]);
      float4 wv[4];
#pragma unroll
      for (int kk = 0; kk < 4; ++kk)
        wv[kk] = *reinterpret_cast<const float4*>(&wl[(k + kk) * 128 + cg * 4]);
#pragma unroll
      for (int rr = 0; rr < 2; ++rr) {
        const float a0 = av[rr].x, a1 = av[rr].y, a2 = av[rr].z, a3 = av[rr].w;
        acc[rr][0] = fmaf(a3, wv[3].x, fmaf(a2, wv[2].x,
                     fmaf(a1, wv[1].x, fmaf(a0, wv[0].x, acc[rr][0]))));
        acc[rr][1] = fmaf(a3, wv[3].y, fmaf(a2, wv[2].y,
                     fmaf(a1, wv[1].y, fmaf(a0, wv[0].y, acc[rr][1]))));
        acc[rr][2] = fmaf(a3, wv[3].z, fmaf(a2, wv[2].z,
                     fmaf(a1, wv[1].z, fmaf(a0, wv[0].z, acc[rr][2]))));
        acc[rr][3] = fmaf(a3, wv[3].w, fmaf(a2, wv[2].w,
                     fmaf(a1, wv[1].w, fmaf(a0, wv[0].w, acc[rr][3]))));
      }
    }
  }
#pragma unroll
  for (int rr = 0; rr < 2; ++rr) {
    const size_t row = (size_t)(m0 + rg * 2 + rr);
#pragma unroll
    for (int cc = 0; cc < 4; ++cc)
      out[row * 131 + 3 + cg * 4 + cc] = fmaxf(acc[rr][cc], 0.0f);
  }
}

// ---------------------------------------------------------------------------
extern "C" void kernel_launch(void* const* d_in, const int* in_sizes, int n_in,
                              void* d_out, int out_size, void* d_ws, size_t ws_size,
                              hipStream_t stream) {
  const float* clouds = (const float*)d_in[0];
  const float* w1a = (const float*)d_in[1];
  const float* w2a = (const float*)d_in[2];
  const float* w1b = (const float*)d_in[3];
  const float* w2b = (const float*)d_in[4];
  const float* wfu = (const float*)d_in[5];
  float* out = (float*)d_out;

  const int B = 2;
  const int N = in_sizes[0] / (4 * B);  // 16384
  const int K = out_size / (131 * B);   // 4096
  const int BK = B * K;                 // 8192

  char* ws = (char*)d_ws;
  u32* order = (u32*)ws;                                  // B*N u32
  size_t off = ((size_t)B * N * sizeof(u32) + 255) & ~(size_t)255;
  u32* bends = (u32*)(ws + off);                          // B*2048 u32
  off += (size_t)B * 2048 * sizeof(u32);
  off = (off + 255) & ~(size_t)255;
  float* meta = (float*)(ws + off);                       // B*8 f32
  off += (size_t)B * 8 * sizeof(float);
  off = (off + 255) & ~(size_t)255;
  float* keyp = (float*)(ws + off);                       // BK*3 f32
  off += (size_t)BK * 3 * sizeof(float);
  off = (off + 255) & ~(size_t)255;
  float* pooled = (float*)(ws + off);                     // BK*512 f32

  k_sort<<<dim3(B), dim3(SORT_T), 0, stream>>>(clouds, order, bends, meta, N);
  k_fps<<<dim3(B), dim3(FPS_T), 0, stream>>>(clouds, order, keyp, N, K);
  k_ballpool<<<dim3(BK), dim3(BP_T), 0, stream>>>(clouds, keyp, order, bends,
                                                  meta, w1a, w2a, w1b, w2b,
                                                  pooled, out, N, K);
  k_fuse<<<dim3(BK / 16), dim3(256), 0, stream>>>(pooled, wfu, out);
}